// Round 9
// baseline (37.496 us; speedup 1.0000x reference)
//
#include <hip/hip_runtime.h>

#define IMG_H 1024
#define IMG_W 1024
#define NIMG  16
#define NPIX  16777216.0f   // 16*1024*1024
#define NBLK  1024          // blocks; 64 per image
#define KSTR  4             // 4-row strips per block (pipelined)
#define LOG2E 1.44269504088896340736f
#define LN2   0.69314718055994530942f

// ws layout: one float4 per block {bce, inter, sum_p, sum_t}. 1024*16B = 16 KB.
// Block b -> image b>>6, strips q = (b&63) + 64k, k=0..3, rows r0 = 4q.

__global__ __launch_bounds__(256, 2) void dal_main(
    const float* __restrict__ xlogits,
    const float* __restrict__ gmask,
    const float* __restrict__ fuse,
    float4* __restrict__ ws4)
{
    const int b    = blockIdx.x;
    const int img  = b >> 6;
    const int qb   = b & 63;
    const int tid  = (int)threadIdx.x;
    const int lane = tid & 63;
    const int j0   = tid * 4;

    const float w0 = fuse[0], w1 = fuse[1], w2 = fuse[2];

    const size_t ibase = (size_t)img * (IMG_H * IMG_W);
    const float* gi = gmask + ibase;
    const float* xi = xlogits + ibase;

    // Overlapping-load halo: per row, float4 at j0-1 and j0+1 (clamped at
    // edges, fixed with cndmask). Covers cols j0-1 .. j0+4.
    const int  jl   = (j0 > 0) ? (j0 - 1) : 0;
    const int  jr1  = (j0 + 4 < IMG_W) ? (j0 + 1) : (IMG_W - 4);
    const bool hasL = (j0 > 0);
    const bool hasR = (j0 + 4 < IMG_W);

    // Double-buffered register staging (named buffers, static indexing only)
    float4 gaA[6], gbA[6], xvA[4];
    float4 gaB[6], gbB[6], xvB[4];

    float l2[2]  = {0.f, 0.f}, xt[2] = {0.f, 0.f};
    float itr[2] = {0.f, 0.f}, sp[2] = {0.f, 0.f};
    int st = 0;

    auto issue = [&](int q, float4 (&ga)[6], float4 (&gb)[6], float4 (&xv)[4]) {
        const int r0 = q << 2;
        #pragma unroll
        for (int t = 0; t < 6; ++t) {
            int r  = r0 - 1 + t;
            int rc = r < 0 ? 0 : (r > IMG_H - 1 ? IMG_H - 1 : r);
            const float* row = gi + (size_t)rc * IMG_W;
            ga[t] = *reinterpret_cast<const float4*>(row + jl);
            gb[t] = *reinterpret_cast<const float4*>(row + jr1);
        }
        const float* xr = xi + (size_t)r0 * IMG_W + j0;
        #pragma unroll
        for (int r = 0; r < 4; ++r)
            xv[r] = *reinterpret_cast<const float4*>(xr + (size_t)r * IMG_W);
    };

    auto px = [&](float x, float btv, float b2v, int a) {
        float f = fmaf(w0, btv, b2v);
        bool  c = f > 0.1f;
        st += (int)__popcll(__ballot(c));
        float u   = __builtin_amdgcn_exp2f(x * LOG2E);   // e^x
        float opu = 1.f + u;
        float p   = u * __builtin_amdgcn_rcpf(opu);      // sigmoid(x)
        l2[a]  += __builtin_amdgcn_logf(opu);            // log2(1+e^x)
        sp[a]  += p;
        xt[a]  += c ? x : 0.f;
        itr[a] += c ? p : 0.f;
    };

    auto compute = [&](int q, float4 (&ga)[6], float4 (&gb)[6], float4 (&xv)[4]) {
        const int r0 = q << 2;
        float rm[6][4], cv[4][4];
        #pragma unroll
        for (int t = 0; t < 6; ++t) {
            float c0 = hasL ? ga[t].x : 0.f;      // col j0-1
            float c1 = hasL ? ga[t].y : ga[t].x;  // col j0
            float c2 = hasL ? ga[t].z : ga[t].y;  // col j0+1
            float c3 = hasL ? ga[t].w : ga[t].z;  // col j0+2
            float c4 = hasR ? gb[t].z : gb[t].w;  // col j0+3
            float c5 = hasR ? gb[t].w : 0.f;      // col j0+4
            rm[t][0] = fminf(c0, fminf(c1, c2));
            rm[t][1] = fminf(c1, fminf(c2, c3));
            rm[t][2] = fminf(c2, fminf(c3, c4));
            rm[t][3] = fminf(c3, fminf(c4, c5));
            if (t >= 1 && t <= 4) {
                cv[t - 1][0] = c1; cv[t - 1][1] = c2;
                cv[t - 1][2] = c3; cv[t - 1][3] = c4;
            }
        }
        // vertical zero padding (block-uniform, first/last strip of image)
        if (r0 == 0)         { rm[0][0] = rm[0][1] = rm[0][2] = rm[0][3] = 0.f; }
        if (r0 == IMG_H - 4) { rm[5][0] = rm[5][1] = rm[5][2] = rm[5][3] = 0.f; }

        float bt[4][4];
        #pragma unroll
        for (int r = 0; r < 4; ++r)
            #pragma unroll
            for (int k = 0; k < 4; ++k) {
                float cm = fminf(rm[r][k], fminf(rm[r + 1][k], rm[r + 2][k]));
                bt[r][k] = (cv[r][k] > 0.5f && cm < 0.5f) ? 1.f : 0.f;
            }

        // bt4 center = (r0, j0) = bt[0][0]; bt2 = bt(r0+(r&~1), j0+(k&~1))
        const float wb4 = w2 * bt[0][0];
        float base2[2][2];
        base2[0][0] = fmaf(w1, bt[0][0], wb4);
        base2[0][1] = fmaf(w1, bt[0][2], wb4);
        base2[1][0] = fmaf(w1, bt[2][0], wb4);
        base2[1][1] = fmaf(w1, bt[2][2], wb4);

        #pragma unroll
        for (int r = 0; r < 4; ++r) {
            const float bA = base2[r >> 1][0];
            const float bB = base2[r >> 1][1];
            px(xv[r].x, bt[r][0], bA, r & 1);
            px(xv[r].y, bt[r][1], bA, r & 1);
            px(xv[r].z, bt[r][2], bB, r & 1);
            px(xv[r].w, bt[r][3], bB, r & 1);
        }
    };

    // ---- software pipeline: issue(k+1) before compute(k), alternating buffers
    issue(qb, gaA, gbA, xvA);
    #pragma unroll
    for (int k = 0; k < KSTR; ++k) {
        if ((k & 1) == 0) {
            if (k < KSTR - 1) issue(qb + 64 * (k + 1), gaB, gbB, xvB);
            compute(qb + 64 * k, gaA, gbA, xvA);
        } else {
            if (k < KSTR - 1) issue(qb + 64 * (k + 1), gaA, gbA, xvA);
            compute(qb + 64 * k, gaB, gbB, xvB);
        }
    }

    float bce   = fmaf(LN2, l2[0] + l2[1], -(xt[0] + xt[1]));
    float inter = itr[0] + itr[1];
    float sump  = sp[0] + sp[1];

    // wave64 reduce (st is wave-uniform via ballot), cross-wave via LDS
    #pragma unroll
    for (int off = 32; off > 0; off >>= 1) {
        bce   += __shfl_down(bce, off);
        inter += __shfl_down(inter, off);
        sump  += __shfl_down(sump, off);
    }
    __shared__ float red[4][4];
    const int wid = tid >> 6;
    if (lane == 0) {
        red[0][wid] = bce; red[1][wid] = inter;
        red[2][wid] = sump; red[3][wid] = (float)st;
    }
    __syncthreads();
    if (tid == 0) {
        float4 o;
        o.x = red[0][0] + red[0][1] + red[0][2] + red[0][3];
        o.y = red[1][0] + red[1][1] + red[1][2] + red[1][3];
        o.z = red[2][0] + red[2][1] + red[2][2] + red[2][3];
        o.w = red[3][0] + red[3][1] + red[3][2] + red[3][3];
        ws4[b] = o;
    }
}

// 1 block, 1024 threads. Thread t reads ws4[t]; wave w = t>>6 covers slots
// [64w, 64w+64) == exactly image w (64 blocks per image). Wave-reduce,
// per-image dice, combine across the 16 waves via LDS.
__global__ __launch_bounds__(1024) void dal_finalize(
    const float4* __restrict__ ws4, float* __restrict__ out)
{
    const int t    = (int)threadIdx.x;
    const int wv   = t >> 6;      // wave id == image id
    const int lane = t & 63;

    float4 a = ws4[t];
    float bce   = a.x;
    float inter = a.y;
    float sump  = a.z;
    float sumt  = a.w;

    #pragma unroll
    for (int off = 32; off > 0; off >>= 1) {
        bce   += __shfl_down(bce, off);
        inter += __shfl_down(inter, off);
        sump  += __shfl_down(sump, off);
        sumt  += __shfl_down(sumt, off);
    }

    __shared__ float sb[16], sd[16];
    if (lane == 0) {
        sb[wv] = bce;
        sd[wv] = 1.f - (2.f * inter + 1.f) / (sump + sumt + 1.f);
    }
    __syncthreads();
    if (t == 0) {
        float tb = 0.f, td = 0.f;
        #pragma unroll
        for (int i = 0; i < NIMG; ++i) { tb += sb[i]; td += sd[i]; }
        out[0] = tb / NPIX;
        out[1] = td / (float)NIMG;
    }
}

extern "C" void kernel_launch(void* const* d_in, const int* in_sizes, int n_in,
                              void* d_out, int out_size, void* d_ws, size_t ws_size,
                              hipStream_t stream)
{
    const float* x    = (const float*)d_in[0];  // boundary_logits [16,1,1024,1024]
    const float* g    = (const float*)d_in[1];  // gtmasks        [16,1024,1024]
    const float* fuse = (const float*)d_in[2];  // fuse_kernel    [3]
    float* out = (float*)d_out;
    float4* ws4 = (float4*)d_ws;

    dal_main<<<NBLK, 256, 0, stream>>>(x, g, fuse, ws4);
    dal_finalize<<<1, 1024, 0, stream>>>(ws4, out);
}

// Round 10
// 30.732 us; speedup vs baseline: 1.2201x; 1.2201x over previous
//
#include <hip/hip_runtime.h>

#define IMG_H 1024
#define IMG_W 1024
#define NIMG  16
#define NPIX  16777216.0f   // 16*1024*1024
#define NBLK  1024          // 64 blocks per image, 16 contiguous rows each
#define LOG2E 1.44269504088896340736f
#define LN2   0.69314718055994530942f

// ws layout: one float4 per block {bce, inter, sum_p, sum_t}. 1024*16B = 16 KB.

__global__ __launch_bounds__(256) void dal_main(
    const float* __restrict__ xlogits,
    const float* __restrict__ gmask,
    const float* __restrict__ fuse,
    float4* __restrict__ ws4)
{
    const int b    = blockIdx.x;
    const int img  = b >> 6;
    const int r0   = (b & 63) << 4;     // rows r0 .. r0+15 (contiguous)
    const int tid  = (int)threadIdx.x;
    const int lane = tid & 63;
    const int j0   = tid * 4;

    const float w0 = fuse[0], w1 = fuse[1], w2 = fuse[2];

    const size_t ibase = (size_t)img * (IMG_H * IMG_W);
    const float* gi = gmask + ibase;
    const float* xi = xlogits + ibase;

    // Overlapping-load halo: per row, float4 at j0-1 and j0+1 (clamped at
    // edges, fixed with cndmask). Covers cols j0-1 .. j0+4.
    const int  jl   = (j0 > 0) ? (j0 - 1) : 0;
    const int  jr1  = (j0 + 4 < IMG_W) ? (j0 + 1) : (IMG_W - 4);
    const bool hasL = (j0 > 0);
    const bool hasR = (j0 + 4 < IMG_W);

    auto loadrow = [&](int r, float4& ga, float4& gb) {
        int rc = r < 0 ? 0 : (r > IMG_H - 1 ? IMG_H - 1 : r);
        const float* row = gi + (size_t)rc * IMG_W;
        ga = *reinterpret_cast<const float4*>(row + jl);
        gb = *reinterpret_cast<const float4*>(row + jr1);
    };
    auto fold = [&](const float4 ga, const float4 gb, float* rm, float* cvo) {
        float c0 = hasL ? ga.x : 0.f;      // col j0-1 (0 at left edge)
        float c1 = hasL ? ga.y : ga.x;     // col j0
        float c2 = hasL ? ga.z : ga.y;     // col j0+1
        float c3 = hasL ? ga.w : ga.z;     // col j0+2
        float c4 = hasR ? gb.z : gb.w;     // col j0+3
        float c5 = hasR ? gb.w : 0.f;      // col j0+4 (0 at right edge)
        rm[0] = fminf(c0, fminf(c1, c2));
        rm[1] = fminf(c1, fminf(c2, c3));
        rm[2] = fminf(c2, fminf(c3, c4));
        rm[3] = fminf(c3, fminf(c4, c5));
        cvo[0] = c1; cvo[1] = c2; cvo[2] = c3; cvo[3] = c4;
    };

    // ---- prologue: halo rows r0-1, r0 + group-0 mask rows r0+1..r0+4
    float4 hga0, hgb0, hga1, hgb1;
    loadrow(r0 - 1, hga0, hgb0);
    loadrow(r0,     hga1, hgb1);
    float4 mgaA[4], mgbA[4], mgaB[4], mgbB[4];
    #pragma unroll
    for (int t = 0; t < 4; ++t) loadrow(r0 + 1 + t, mgaA[t], mgbA[t]);

    // carried rolling state: rmA_ = rm(R-1), rmB_ = rm(R), cvC = cv(R)
    float rmA_[4], rmB_[4], cvC[4];
    {
        float tmp[4];
        fold(hga0, hgb0, rmA_, tmp);
        if (r0 == 0) { rmA_[0] = rmA_[1] = rmA_[2] = rmA_[3] = 0.f; }
        fold(hga1, hgb1, rmB_, cvC);
    }

    float l2[2]  = {0.f, 0.f}, xt[2] = {0.f, 0.f};
    float itr[2] = {0.f, 0.f}, sp[2] = {0.f, 0.f};
    int st = 0;

    auto px = [&](float x, float btv, float b2v, int a) {
        float f = fmaf(w0, btv, b2v);
        bool  c = f > 0.1f;
        st += (int)__popcll(__ballot(c));
        float u   = __builtin_amdgcn_exp2f(x * LOG2E);   // e^x
        float opu = 1.f + u;
        float p   = u * __builtin_amdgcn_rcpf(opu);      // sigmoid(x)
        l2[a]  += __builtin_amdgcn_logf(opu);            // log2(1+e^x)
        sp[a]  += p;
        xt[a]  += c ? x : 0.f;
        itr[a] += c ? p : 0.f;
    };

    // ---- 4 groups of 4 rows, rolling window, A/B mask-load double-buffer
    #pragma unroll
    for (int g = 0; g < 4; ++g) {
        const int R = r0 + 4 * g;

        // issue x loads (consumed at the END of this group)
        float4 xv[4];
        const float* xr = xi + (size_t)R * IMG_W + j0;
        #pragma unroll
        for (int r = 0; r < 4; ++r)
            xv[r] = *reinterpret_cast<const float4*>(xr + (size_t)r * IMG_W);

        // issue NEXT group's mask loads (consumed next iteration)
        if (g < 3) {
            if ((g & 1) == 0) {
                #pragma unroll
                for (int t = 0; t < 4; ++t) loadrow(R + 5 + t, mgaB[t], mgbB[t]);
            } else {
                #pragma unroll
                for (int t = 0; t < 4; ++t) loadrow(R + 5 + t, mgaA[t], mgbA[t]);
            }
        }

        // fold current buffer -> rm/cv of rows R+1..R+4
        float frm0[4], frm1[4], frm2[4], frm3[4];
        float fcv0[4], fcv1[4], fcv2[4], fcv3[4];
        if ((g & 1) == 0) {
            fold(mgaA[0], mgbA[0], frm0, fcv0);
            fold(mgaA[1], mgbA[1], frm1, fcv1);
            fold(mgaA[2], mgbA[2], frm2, fcv2);
            fold(mgaA[3], mgbA[3], frm3, fcv3);
        } else {
            fold(mgaB[0], mgbB[0], frm0, fcv0);
            fold(mgaB[1], mgbB[1], frm1, fcv1);
            fold(mgaB[2], mgbB[2], frm2, fcv2);
            fold(mgaB[3], mgbB[3], frm3, fcv3);
        }
        // vertical zero padding: row R+4 == IMG_H is an all-zero pad row
        {
            const bool padB = (R + 4 == IMG_H);
            #pragma unroll
            for (int k = 0; k < 4; ++k) frm3[k] = padB ? 0.f : frm3[k];
        }

        // bt rows R..R+3:  bt = (g==1) && (min3x3 == 0)
        float bt[4][4];
        #pragma unroll
        for (int k = 0; k < 4; ++k) {
            float cm0 = fminf(rmA_[k], fminf(rmB_[k], frm0[k]));
            float cm1 = fminf(rmB_[k], fminf(frm0[k], frm1[k]));
            float cm2 = fminf(frm0[k], fminf(frm1[k], frm2[k]));
            float cm3 = fminf(frm1[k], fminf(frm2[k], frm3[k]));
            bt[0][k] = (cvC[k]  > 0.5f && cm0 < 0.5f) ? 1.f : 0.f;
            bt[1][k] = (fcv0[k] > 0.5f && cm1 < 0.5f) ? 1.f : 0.f;
            bt[2][k] = (fcv1[k] > 0.5f && cm2 < 0.5f) ? 1.f : 0.f;
            bt[3][k] = (fcv2[k] > 0.5f && cm3 < 0.5f) ? 1.f : 0.f;
        }

        // carry rolling state for next group (rows R+3, R+4 mins; cv(R+4))
        #pragma unroll
        for (int k = 0; k < 4; ++k) {
            rmA_[k] = frm2[k]; rmB_[k] = frm3[k]; cvC[k] = fcv3[k];
        }

        // R % 4 == 0: bt4 center = (R, j0) = bt[0][0];
        // bt2 = bt(R + (r&~1), j0 + (k&~1))
        const float wb4 = w2 * bt[0][0];
        float base2[2][2];
        base2[0][0] = fmaf(w1, bt[0][0], wb4);
        base2[0][1] = fmaf(w1, bt[0][2], wb4);
        base2[1][0] = fmaf(w1, bt[2][0], wb4);
        base2[1][1] = fmaf(w1, bt[2][2], wb4);

        #pragma unroll
        for (int r = 0; r < 4; ++r) {
            const float bA = base2[r >> 1][0];
            const float bB = base2[r >> 1][1];
            px(xv[r].x, bt[r][0], bA, r & 1);
            px(xv[r].y, bt[r][1], bA, r & 1);
            px(xv[r].z, bt[r][2], bB, r & 1);
            px(xv[r].w, bt[r][3], bB, r & 1);
        }
    }

    float bce   = fmaf(LN2, l2[0] + l2[1], -(xt[0] + xt[1]));
    float inter = itr[0] + itr[1];
    float sump  = sp[0] + sp[1];

    // wave64 reduce (st is wave-uniform via ballot), cross-wave via LDS
    #pragma unroll
    for (int off = 32; off > 0; off >>= 1) {
        bce   += __shfl_down(bce, off);
        inter += __shfl_down(inter, off);
        sump  += __shfl_down(sump, off);
    }
    __shared__ float red[4][4];
    const int wid = tid >> 6;
    if (lane == 0) {
        red[0][wid] = bce; red[1][wid] = inter;
        red[2][wid] = sump; red[3][wid] = (float)st;
    }
    __syncthreads();
    if (tid == 0) {
        float4 o;
        o.x = red[0][0] + red[0][1] + red[0][2] + red[0][3];
        o.y = red[1][0] + red[1][1] + red[1][2] + red[1][3];
        o.z = red[2][0] + red[2][1] + red[2][2] + red[2][3];
        o.w = red[3][0] + red[3][1] + red[3][2] + red[3][3];
        ws4[b] = o;
    }
}

// 1 block, 1024 threads. Thread t reads ws4[t]; wave w = t>>6 covers slots
// [64w, 64w+64) == exactly image w (64 blocks per image). Wave-reduce,
// per-image dice, combine across the 16 waves via LDS.
__global__ __launch_bounds__(1024) void dal_finalize(
    const float4* __restrict__ ws4, float* __restrict__ out)
{
    const int t    = (int)threadIdx.x;
    const int wv   = t >> 6;      // wave id == image id
    const int lane = t & 63;

    float4 a = ws4[t];
    float bce   = a.x;
    float inter = a.y;
    float sump  = a.z;
    float sumt  = a.w;

    #pragma unroll
    for (int off = 32; off > 0; off >>= 1) {
        bce   += __shfl_down(bce, off);
        inter += __shfl_down(inter, off);
        sump  += __shfl_down(sump, off);
        sumt  += __shfl_down(sumt, off);
    }

    __shared__ float sb[16], sd[16];
    if (lane == 0) {
        sb[wv] = bce;
        sd[wv] = 1.f - (2.f * inter + 1.f) / (sump + sumt + 1.f);
    }
    __syncthreads();
    if (t == 0) {
        float tb = 0.f, td = 0.f;
        #pragma unroll
        for (int i = 0; i < NIMG; ++i) { tb += sb[i]; td += sd[i]; }
        out[0] = tb / NPIX;
        out[1] = td / (float)NIMG;
    }
}

extern "C" void kernel_launch(void* const* d_in, const int* in_sizes, int n_in,
                              void* d_out, int out_size, void* d_ws, size_t ws_size,
                              hipStream_t stream)
{
    const float* x    = (const float*)d_in[0];  // boundary_logits [16,1,1024,1024]
    const float* g    = (const float*)d_in[1];  // gtmasks        [16,1024,1024]
    const float* fuse = (const float*)d_in[2];  // fuse_kernel    [3]
    float* out = (float*)d_out;
    float4* ws4 = (float4*)d_ws;

    dal_main<<<NBLK, 256, 0, stream>>>(x, g, fuse, ws4);
    dal_finalize<<<1, 1024, 0, stream>>>(ws4, out);
}